// Round 2
// baseline (240.399 us; speedup 1.0000x reference)
//
#include <hip/hip_runtime.h>
#include <stdint.h>

// Problem constants
#define NMOL 4096
#define NATOMS (NMOL * 64)     // 262144
#define NF 124
#define NT 8
#define ROWV 125               // x_padded row stride in floats
#define CAP 65536              // list slots per type (worst case all atoms one type)

// ws layout (bytes)
#define WS_DCONST  0           // float[8]   (= T - c_t + b3_t)
#define WS_CURSOR  64          // uint[8]    (preset to t*CAP; post-sort = t*CAP + count_t)
#define WS_W1S     128         // ushort[8*64*128] bf16, UNSWIZZLED [t][h][f/8 chunks] (128 KB)
#define WS_W2T     131200      // ushort[8*16*64]  bf16, [t][g][h]       (16 KB)
#define WS_LIST    147712      // uint[NT*CAP]                           (2 MB)

#define HS 72                  // h1 row stride in shorts

typedef __attribute__((ext_vector_type(8))) short short8;
typedef __attribute__((ext_vector_type(4))) float floatx4;
typedef __attribute__((ext_vector_type(4), aligned(4))) float floatx4u;  // 4B-aligned vec load
typedef __attribute__((ext_vector_type(4))) unsigned int uint4v;

__device__ __forceinline__ unsigned short f2bf(float f) {
    unsigned u = __builtin_bit_cast(unsigned, f);
    u += 0x7fffu + ((u >> 16) & 1u);
    return (unsigned short)(u >> 16);
}
__device__ __forceinline__ unsigned pk2(float a, float b) {
    return (unsigned)f2bf(a) | ((unsigned)f2bf(b) << 16);
}

// ---------------- K1: setup (constants + cursors + weight prep + out-zero) ----------------
// b==0: dconst fp32 + cursor[t]=t*CAP
// b 1..32: W1S/W2T prep, 4 blocks per type (t=(b-1)>>2, sub=(b-1)&3)
// b 33..48: zero out
__global__ __launch_bounds__(256) void k_setup(const float* __restrict__ W1,
                                               const float* __restrict__ b1,
                                               const float* __restrict__ W2,
                                               const float* __restrict__ b2,
                                               const float* __restrict__ W3,
                                               const float* __restrict__ b3,
                                               float* __restrict__ dconst,
                                               unsigned* __restrict__ cursor,
                                               unsigned short* __restrict__ W1S,
                                               unsigned short* __restrict__ W2T,
                                               float* __restrict__ out) {
    int tid = threadIdx.x, b = blockIdx.x;
    if (b == 0) {
        __shared__ float c[NT];
        if (tid < 128) {           // exact fp32 constant c_t = MLP_t(0)
            int t = tid >> 4, g = tid & 15;
            float acc = b2[t * 16 + g];
            for (int h = 0; h < 64; ++h) {
                float h1 = b1[t * 64 + h];
                h1 = h1 > 0.f ? h1 : 0.f;
                acc += h1 * W2[(size_t)t * 1024 + h * 16 + g];
            }
            float h2 = acc > 0.f ? acc : 0.f;
            float v = h2 * W3[t * 16 + g];
            #pragma unroll
            for (int off = 1; off < 16; off <<= 1) v += __shfl_xor(v, off);
            if (g == 0) c[t] = v + b3[t];
        }
        if (tid < NT) cursor[tid] = (unsigned)(tid * CAP);
        __syncthreads();
        if (tid == 0) {
            float T_ = 0.f;
            for (int i = 0; i < NT; ++i) T_ += c[i];
            for (int i = 0; i < NT; ++i) dconst[i] = T_ - c[i] + b3[i];
        }
    } else if (b <= 32) {
        int t = (b - 1) >> 2, sub = (b - 1) & 3;
        // W1 -> W1S: [h][cc][8 shorts], f padded to 128 w/ zeros (UNSWIZZLED)
        const float* w1g = W1 + (size_t)t * NF * 64;
        unsigned short* dst = W1S + (size_t)t * 8192;
        {
            int id = sub * 256 + tid;            // 0..1023
            int h = id >> 4, cc = id & 15;
            unsigned u[4];
            #pragma unroll
            for (int j = 0; j < 4; ++j) {
                int f0 = cc * 8 + 2 * j;
                unsigned short lo = (f0 < NF)     ? f2bf(w1g[f0 * 64 + h])       : (unsigned short)0;
                unsigned short hi = (f0 + 1 < NF) ? f2bf(w1g[(f0 + 1) * 64 + h]) : (unsigned short)0;
                u[j] = (unsigned)lo | ((unsigned)hi << 16);
            }
            *(uint4v*)(dst + h * 128 + cc * 8) = (uint4v){u[0], u[1], u[2], u[3]};
        }
        // W2 -> W2T: [t][g][h], 256 elems per sub-block
        {
            int i = sub * 256 + tid;
            int g = i >> 6, h = i & 63;
            W2T[(size_t)t * 1024 + i] = f2bf(W2[(size_t)t * 1024 + h * 16 + g]);
        }
    } else {
        out[(b - 33) * 256 + tid] = 0.0f;
    }
}

// ---------------- K2: one-pass type sort, ballot-histogram, 1 atom/thread ----------------
__global__ __launch_bounds__(256) void k_sort(const float* __restrict__ x,
                                              const float* __restrict__ mask,
                                              unsigned* __restrict__ cursor,
                                              unsigned* __restrict__ list) {
    __shared__ unsigned scnt[4][NT];
    __shared__ unsigned sbase[4][NT];
    int tid = threadIdx.x;
    int wv = tid >> 6, lane = tid & 63;
    int atom = blockIdx.x * 256 + tid;

    float tf = x[(size_t)atom * ROWV];
    float m  = mask[atom];
    int tt = (m != 0.0f) ? (int)tf : -1;

    unsigned long long bm = 0ull;
    unsigned mycnt = 0;
    #pragma unroll
    for (int ty = 0; ty < NT; ++ty) {
        unsigned long long b = __ballot(tt == ty);
        if (ty == tt) bm = b;
        if (lane == ty) mycnt = (unsigned)__popcll(b);
    }
    if (lane < NT) scnt[wv][lane] = mycnt;
    __syncthreads();
    if (tid < NT) {
        unsigned tot = 0;
        #pragma unroll
        for (int w = 0; w < 4; ++w) tot += scnt[w][tid];
        unsigned run = atomicAdd(&cursor[tid], tot);
        #pragma unroll
        for (int w = 0; w < 4; ++w) { sbase[w][tid] = run; run += scnt[w][tid]; }
    }
    __syncthreads();
    if (tt >= 0) {
        unsigned rank = (unsigned)__popcll(bm & ((1ull << lane) - 1ull));
        list[sbase[wv][tt] + rank] = (unsigned)atom;
    }
}

// ---------------- K3: MLP over type-sorted atoms — ZERO barriers ----------------
// Block = 128 sorted atoms of ONE type. Consecutive blocks are same-type, so the
// 16 KB W1S[t] tile is L1-resident: B-fragments are read straight from global,
// removing the LDS staging + the only __syncthreads. sH is strictly wave-local
// (rows [wv*32, wv*32+32)), so no inter-wave sync is needed at all.
__global__ __launch_bounds__(256, 4) void k_mlp(const float* __restrict__ x,
                                                const unsigned short* __restrict__ W1S,
                                                const float* __restrict__ b1,
                                                const unsigned short* __restrict__ W2T,
                                                const float* __restrict__ b2,
                                                const float* __restrict__ W3,
                                                const unsigned* __restrict__ cursor,
                                                const float* __restrict__ dconst,
                                                const unsigned* __restrict__ list,
                                                float* __restrict__ out) {
    __shared__ unsigned short sH[128 * HS];   // h1 bf16 (18 KB)

    int t    = blockIdx.x >> 9;               // 512 tiles per type segment
    int tile = blockIdx.x & 511;
    int cnt  = (int)(cursor[t] - (unsigned)(t * CAP));
    int valid = cnt - (tile << 7);
    if (valid <= 0) return;
    if (valid > 128) valid = 128;
    int rowstart = t * CAP + (tile << 7);

    int tid  = threadIdx.x;
    int wv   = tid >> 6;
    int lane = tid & 63;
    int quad = lane >> 4, l15 = lane & 15;
    int rowbase = wv * 32;

    // ---- gather ids straight from global (L2-hot) ----
    unsigned aid[2];
    #pragma unroll
    for (int m = 0; m < 2; ++m) {
        int row = rowbase + m * 16 + l15;
        aid[m] = list[rowstart + (row < valid ? row : 0)];   // clamp OOB rows
    }

    // hoist small L2-hot operands while gathers will be in flight
    float b1v[4];
    #pragma unroll
    for (int n = 0; n < 4; ++n) b1v[n] = b1[t * 64 + n * 16 + l15];
    const unsigned short* w2t = W2T + (size_t)t * 1024;
    short8 bw2[2];
    #pragma unroll
    for (int ks = 0; ks < 2; ++ks)
        bw2[ks] = *(const short8*)(w2t + l15 * 64 + ks * 32 + quad * 8);
    float b2v = b2[t * 16 + l15];
    float w3v = W3[t * 16 + l15];
    float dct = dconst[t];   // includes b3

    // ---- A-fragments: gather rows straight into regs, bf16 once ----
    short8 afrag[2][4];
    #pragma unroll
    for (int m = 0; m < 2; ++m) {
        const float* rp = x + (size_t)aid[m] * ROWV + 1;
        #pragma unroll
        for (int ks = 0; ks < 4; ++ks) {
            int k0 = ks * 32 + quad * 8;
            floatx4 f0 = (floatx4)(*(const floatx4u*)(rp + k0));
            floatx4 f1 = (floatx4)0.f;
            if (!(ks == 3 && quad == 3))         // f>=124 pad; W1S pad rows are zero
                f1 = (floatx4)(*(const floatx4u*)(rp + k0 + 4));
            uint4v uu = (uint4v){pk2(f0[0], f0[1]), pk2(f0[2], f0[3]),
                                 pk2(f1[0], f1[1]), pk2(f1[2], f1[3])};
            afrag[m][ks] = __builtin_bit_cast(short8, uu);
        }
    }

    // ---- layer 1: [32x128] x [128x64], B-frags from global (L1-hot, 16 KB/type) ----
    const unsigned short* w1t = W1S + (size_t)t * 8192;
    floatx4 c1[2][4];
    #pragma unroll
    for (int m = 0; m < 2; ++m)
        #pragma unroll
        for (int n = 0; n < 4; ++n) c1[m][n] = (floatx4)0.f;

    #pragma unroll
    for (int ks = 0; ks < 4; ++ks) {
        short8 bf[4];
        #pragma unroll
        for (int n = 0; n < 4; ++n)
            bf[n] = *(const short8*)(w1t + (n * 16 + l15) * 128 + (ks * 4 + quad) * 8);
        #pragma unroll
        for (int n = 0; n < 4; ++n) {
            c1[0][n] = __builtin_amdgcn_mfma_f32_16x16x32_bf16(afrag[0][ks], bf[n], c1[0][n], 0, 0, 0);
            c1[1][n] = __builtin_amdgcn_mfma_f32_16x16x32_bf16(afrag[1][ks], bf[n], c1[1][n], 0, 0, 0);
        }
    }

    // ---- h1 = relu(c1+b1) -> sH (own-wave rows, no barrier) ----
    #pragma unroll
    for (int m = 0; m < 2; ++m)
        #pragma unroll
        for (int n = 0; n < 4; ++n) {
            int col = n * 16 + l15;
            #pragma unroll
            for (int r = 0; r < 4; ++r) {
                float v = c1[m][n][r] + b1v[n];
                v = v > 0.f ? v : 0.f;
                sH[(rowbase + m * 16 + quad * 4 + r) * HS + col] = f2bf(v);
            }
        }

    // ---- layer 2: [32x64] x [64x16] ----
    floatx4 c2[2];
    c2[0] = (floatx4)0.f; c2[1] = (floatx4)0.f;
    #pragma unroll
    for (int ks = 0; ks < 2; ++ks) {
        int ko = ks * 32 + quad * 8;
        short8 a0 = *(const short8*)(sH + (rowbase + l15) * HS + ko);
        short8 a1 = *(const short8*)(sH + (rowbase + 16 + l15) * HS + ko);
        c2[0] = __builtin_amdgcn_mfma_f32_16x16x32_bf16(a0, bw2[ks], c2[0], 0, 0, 0);
        c2[1] = __builtin_amdgcn_mfma_f32_16x16x32_bf16(a1, bw2[ks], c2[1], 0, 0, 0);
    }

    // ---- layer 3 + constant + atomic accumulate ----
    #pragma unroll
    for (int m = 0; m < 2; ++m) {
        float h2v[4];
        #pragma unroll
        for (int r = 0; r < 4; ++r) {
            float v = c2[m][r] + b2v;
            v = v > 0.f ? v : 0.f;
            h2v[r] = v * w3v;
        }
        #pragma unroll
        for (int off = 1; off < 16; off <<= 1)
            #pragma unroll
            for (int r = 0; r < 4; ++r) h2v[r] += __shfl_xor(h2v[r], off);
        if (l15 == 0) {
            #pragma unroll
            for (int r = 0; r < 4; ++r) {
                int row = rowbase + m * 16 + quad * 4 + r;
                if (row < valid) {
                    unsigned atom = list[rowstart + row];
                    atomicAdd(&out[atom >> 6], h2v[r] + dct);
                }
            }
        }
    }
}

extern "C" void kernel_launch(void* const* d_in, const int* in_sizes, int n_in,
                              void* d_out, int out_size, void* d_ws, size_t ws_size,
                              hipStream_t stream) {
    const float* x    = (const float*)d_in[0];
    const float* mask = (const float*)d_in[1];
    const float* W1   = (const float*)d_in[2];
    const float* b1   = (const float*)d_in[3];
    const float* W2   = (const float*)d_in[4];
    const float* b2   = (const float*)d_in[5];
    const float* W3   = (const float*)d_in[6];
    const float* b3   = (const float*)d_in[7];
    float* out = (float*)d_out;

    char* ws = (char*)d_ws;
    float*          dconst = (float*)(ws + WS_DCONST);
    unsigned*       cursor = (unsigned*)(ws + WS_CURSOR);
    unsigned short* W1S    = (unsigned short*)(ws + WS_W1S);
    unsigned short* W2T    = (unsigned short*)(ws + WS_W2T);
    unsigned*       list   = (unsigned*)(ws + WS_LIST);

    k_setup<<<49, 256, 0, stream>>>(W1, b1, W2, b2, W3, b3, dconst, cursor, W1S, W2T, out);
    k_sort<<<1024, 256, 0, stream>>>(x, mask, cursor, list);
    k_mlp<<<NT * (CAP / 128), 256, 0, stream>>>(x, W1S, b1, W2T, b2, W3,
                                                cursor, dconst, list, out);
}

// Round 3
// 220.385 us; speedup vs baseline: 1.0908x; 1.0908x over previous
//
#include <hip/hip_runtime.h>
#include <stdint.h>

// Problem constants
#define NMOL 4096
#define NATOMS (NMOL * 64)     // 262144
#define NF 124
#define NT 8
#define ROWV 125               // x_padded row stride in floats
#define CAP 65536              // list slots per type (worst case all atoms one type)

// ws layout (bytes)
#define WS_DCONST  0           // float[8]   (= T - c_t + b3_t)
#define WS_CURSOR  64          // uint[8]    (preset to t*CAP; post-sort = t*CAP + count_t)
#define WS_W1S     128         // ushort[8*64*128] bf16, XOR-16 swizzled (128 KB)
#define WS_W2T     131200      // ushort[8*16*64]  bf16, [t][g][h]       (16 KB)
#define WS_LIST    147712      // uint[NT*CAP]                           (2 MB)

#define HS 72                  // h1 row stride in shorts

typedef __attribute__((ext_vector_type(8))) short short8;
typedef __attribute__((ext_vector_type(4))) float floatx4;
typedef __attribute__((ext_vector_type(4), aligned(4))) float floatx4u;  // 4B-aligned vec load
typedef __attribute__((ext_vector_type(4))) unsigned int uint4v;

__device__ __forceinline__ unsigned short f2bf(float f) {
    unsigned u = __builtin_bit_cast(unsigned, f);
    u += 0x7fffu + ((u >> 16) & 1u);
    return (unsigned short)(u >> 16);
}
__device__ __forceinline__ unsigned pk2(float a, float b) {
    return (unsigned)f2bf(a) | ((unsigned)f2bf(b) << 16);
}
__device__ __forceinline__ void ld_lds16(const void* g, void* lds) {
    __builtin_amdgcn_global_load_lds(
        (const __attribute__((address_space(1))) unsigned int*)g,
        (__attribute__((address_space(3))) unsigned int*)lds, 16, 0, 0);
}

// ---------------- K1: setup (constants + cursors + weight prep + out-zero) ----------------
// b==0: dconst fp32 + cursor[t]=t*CAP; b 1..8: W1S/W2T for type b-1; b 9..24: zero out
__global__ __launch_bounds__(256) void k_setup(const float* __restrict__ W1,
                                               const float* __restrict__ b1,
                                               const float* __restrict__ W2,
                                               const float* __restrict__ b2,
                                               const float* __restrict__ W3,
                                               const float* __restrict__ b3,
                                               float* __restrict__ dconst,
                                               unsigned* __restrict__ cursor,
                                               unsigned short* __restrict__ W1S,
                                               unsigned short* __restrict__ W2T,
                                               float* __restrict__ out) {
    int tid = threadIdx.x, b = blockIdx.x;
    if (b == 0) {
        __shared__ float c[NT];
        if (tid < 128) {           // exact fp32 constant c_t = MLP_t(0)
            int t = tid >> 4, g = tid & 15;
            float acc = b2[t * 16 + g];
            for (int h = 0; h < 64; ++h) {
                float h1 = b1[t * 64 + h];
                h1 = h1 > 0.f ? h1 : 0.f;
                acc += h1 * W2[(size_t)t * 1024 + h * 16 + g];
            }
            float h2 = acc > 0.f ? acc : 0.f;
            float v = h2 * W3[t * 16 + g];
            #pragma unroll
            for (int off = 1; off < 16; off <<= 1) v += __shfl_xor(v, off);
            if (g == 0) c[t] = v + b3[t];
        }
        if (tid < NT) cursor[tid] = (unsigned)(tid * CAP);
        __syncthreads();
        if (tid == 0) {
            float T_ = 0.f;
            for (int i = 0; i < NT; ++i) T_ += c[i];
            for (int i = 0; i < NT; ++i) dconst[i] = T_ - c[i] + b3[i];
        }
    } else if (b <= 8) {
        int t = b - 1;
        // W1 -> W1S: [h][chunk p = cc ^ (h&15)][8 shorts], f padded to 128 w/ zeros
        const float* w1g = W1 + (size_t)t * NF * 64;
        unsigned short* dst = W1S + (size_t)t * 8192;
        for (int id = tid; id < 1024; id += 256) {
            int h = id >> 4, cc = id & 15;
            unsigned u[4];
            #pragma unroll
            for (int j = 0; j < 4; ++j) {
                int f0 = cc * 8 + 2 * j;
                unsigned short lo = (f0 < NF)     ? f2bf(w1g[f0 * 64 + h])       : (unsigned short)0;
                unsigned short hi = (f0 + 1 < NF) ? f2bf(w1g[(f0 + 1) * 64 + h]) : (unsigned short)0;
                u[j] = (unsigned)lo | ((unsigned)hi << 16);
            }
            int p = cc ^ (h & 15);
            *(uint4v*)(dst + h * 128 + p * 8) = (uint4v){u[0], u[1], u[2], u[3]};
        }
        // W2 -> W2T: [t][g][h]
        unsigned short* d2 = W2T + (size_t)t * 1024;
        for (int i = tid; i < 1024; i += 256) {
            int g = i >> 6, h = i & 63;
            d2[i] = f2bf(W2[(size_t)t * 1024 + h * 16 + g]);
        }
    } else {
        out[(b - 9) * 256 + tid] = 0.0f;
    }
}

// ---------------- K2: one-pass type sort into fixed segments ----------------
__global__ __launch_bounds__(256) void k_sort(const float* __restrict__ x,
                                              const float* __restrict__ mask,
                                              unsigned* __restrict__ cursor,
                                              unsigned* __restrict__ list) {
    __shared__ unsigned hist[NT], basep[NT], cur[NT];
    int tid = threadIdx.x;
    if (tid < NT) { hist[tid] = 0u; cur[tid] = 0u; }
    __syncthreads();
    int base = blockIdx.x * 1024;
    unsigned char tb[4];
    for (int i = 0; i < 4; ++i) {
        int atom = base + i * 256 + tid;
        float tf = x[(size_t)atom * ROWV];
        float m  = mask[atom];
        tb[i] = 0xFF;
        if (m != 0.0f) { tb[i] = (unsigned char)(int)tf; atomicAdd(&hist[tb[i]], 1u); }
    }
    __syncthreads();
    if (tid < NT && hist[tid]) basep[tid] = atomicAdd(&cursor[tid], hist[tid]);
    __syncthreads();
    for (int i = 0; i < 4; ++i) {
        if (tb[i] != 0xFF) {
            unsigned p = basep[tb[i]] + atomicAdd(&cur[tb[i]], 1u);
            list[p] = (unsigned)(base + i * 256 + tid);
        }
    }
}

// ---------------- K3: MLP over type-sorted atoms, A-frags in regs ----------------
// Block = 128 sorted atoms of ONE type. LDS 35.3 KB -> 4 blocks/CU.
// Flat block->(t,tile) mapping over actual tile counts: no early-exit dead blocks.
__global__ __launch_bounds__(256, 4) void k_mlp(const float* __restrict__ x,
                                                const unsigned short* __restrict__ W1S,
                                                const float* __restrict__ b1,
                                                const unsigned short* __restrict__ W2T,
                                                const float* __restrict__ b2,
                                                const float* __restrict__ W3,
                                                const unsigned* __restrict__ cursor,
                                                const float* __restrict__ dconst,
                                                const unsigned* __restrict__ list,
                                                float* __restrict__ out) {
    __shared__ unsigned short sW[64 * 128];   // W1 swizzled (16 KB)
    __shared__ unsigned short sH[128 * HS];   // h1 bf16 (18 KB)
    __shared__ unsigned sIds[128];

    // ---- flat mapping: find (t, tile) from cumulative tile counts (L2-hot, 8 iters) ----
    unsigned cnts[NT];
    #pragma unroll
    for (int i = 0; i < NT; ++i) cnts[i] = cursor[i] - (unsigned)(i * CAP);
    int b = (int)blockIdx.x;
    int t = 0, acc = 0;
    #pragma unroll
    for (int i = 0; i < NT; ++i) {
        int nt_ = (int)((cnts[i] + 127u) >> 7);
        bool in = (b >= acc) && (b < acc + nt_);
        if (in) t = i;
        if (b >= acc + nt_ && i == t) t = i + 1 <= NT - 1 ? t : t;  // no-op; t set by 'in'
        acc += (b >= acc + nt_) ? nt_ : (in ? 0 : 0);
        // recompute cleanly below
    }
    // (clean scalar scan — 8 iterations, branch-free enough)
    {
        int a2 = 0; int tt = -1; int tl = 0;
        #pragma unroll
        for (int i = 0; i < NT; ++i) {
            int nt_ = (int)((cnts[i] + 127u) >> 7);
            if (tt < 0 && b < a2 + nt_) { tt = i; tl = b - a2; }
            a2 += nt_;
        }
        if (tt < 0) return;          // beyond total tiles
        t = tt;
        acc = tl;
    }
    int tile = acc;
    int cnt  = (int)cnts[t];
    int valid = cnt - (tile << 7);
    if (valid <= 0) return;
    if (valid > 128) valid = 128;
    int rowstart = t * CAP + (tile << 7);

    int tid  = threadIdx.x;
    int wv   = tid >> 6;
    int lane = tid & 63;
    int quad = lane >> 4, l15 = lane & 15;
    int rowbase = wv * 32;

    // ---- stage W1S[t] -> sW (async 16B/lane) + ids ----
    {
        const char* src = (const char*)W1S + (size_t)t * 16384 + wv * 4096 + lane * 16;
        char*       dst = (char*)sW + wv * 4096;
        #pragma unroll
        for (int i = 0; i < 4; ++i) ld_lds16(src + i * 1024, dst + i * 1024);
    }
    if (tid < 128) sIds[tid] = list[rowstart + (tid < valid ? tid : 0)];  // clamp OOB rows

    float b1v[4];
    #pragma unroll
    for (int n = 0; n < 4; ++n) b1v[n] = b1[t * 64 + n * 16 + l15];

    __syncthreads();   // drains global_load_lds + sIds visible

    // ---- A-fragments: gather rows straight into regs, bf16 once ----
    short8 afrag[2][4];
    #pragma unroll
    for (int m = 0; m < 2; ++m) {
        unsigned atom = sIds[rowbase + m * 16 + l15];
        const float* rp = x + (size_t)atom * ROWV + 1;
        #pragma unroll
        for (int ks = 0; ks < 4; ++ks) {
            int k0 = ks * 32 + quad * 8;
            floatx4 f0 = (floatx4)(*(const floatx4u*)(rp + k0));
            floatx4 f1 = (floatx4)0.f;
            if (!(ks == 3 && quad == 3))         // f>=124 pad; W1S pad rows are zero
                f1 = (floatx4)(*(const floatx4u*)(rp + k0 + 4));
            uint4v uu = (uint4v){pk2(f0[0], f0[1]), pk2(f0[2], f0[3]),
                                 pk2(f1[0], f1[1]), pk2(f1[2], f1[3])};
            afrag[m][ks] = __builtin_bit_cast(short8, uu);
        }
    }

    // ---- layer 1: [32x128] x [128x64] ----
    floatx4 c1[2][4];
    #pragma unroll
    for (int m = 0; m < 2; ++m)
        #pragma unroll
        for (int n = 0; n < 4; ++n) c1[m][n] = (floatx4)0.f;

    #pragma unroll
    for (int ks = 0; ks < 4; ++ks) {
        short8 bf[4];
        #pragma unroll
        for (int n = 0; n < 4; ++n)
            bf[n] = *(const short8*)(sW + (n * 16 + l15) * 128 + (((ks * 4 + quad) ^ l15) << 3));
        #pragma unroll
        for (int n = 0; n < 4; ++n) {
            c1[0][n] = __builtin_amdgcn_mfma_f32_16x16x32_bf16(afrag[0][ks], bf[n], c1[0][n], 0, 0, 0);
            c1[1][n] = __builtin_amdgcn_mfma_f32_16x16x32_bf16(afrag[1][ks], bf[n], c1[1][n], 0, 0, 0);
        }
    }

    // ---- h1 = relu(c1+b1) -> sH (own-wave rows, no barrier) ----
    #pragma unroll
    for (int m = 0; m < 2; ++m)
        #pragma unroll
        for (int n = 0; n < 4; ++n) {
            int col = n * 16 + l15;
            #pragma unroll
            for (int r = 0; r < 4; ++r) {
                float v = c1[m][n][r] + b1v[n];
                v = v > 0.f ? v : 0.f;
                sH[(rowbase + m * 16 + quad * 4 + r) * HS + col] = f2bf(v);
            }
        }

    // ---- layer 2: [32x64] x [64x16] ----
    const unsigned short* w2t = W2T + (size_t)t * 1024;
    floatx4 c2[2];
    c2[0] = (floatx4)0.f; c2[1] = (floatx4)0.f;
    #pragma unroll
    for (int ks = 0; ks < 2; ++ks) {
        int ko = ks * 32 + quad * 8;
        short8 a0 = *(const short8*)(sH + (rowbase + l15) * HS + ko);
        short8 a1 = *(const short8*)(sH + (rowbase + 16 + l15) * HS + ko);
        short8 bw = *(const short8*)(w2t + l15 * 64 + ko);
        c2[0] = __builtin_amdgcn_mfma_f32_16x16x32_bf16(a0, bw, c2[0], 0, 0, 0);
        c2[1] = __builtin_amdgcn_mfma_f32_16x16x32_bf16(a1, bw, c2[1], 0, 0, 0);
    }

    // ---- layer 3 + constant + atomic accumulate ----
    float b2v = b2[t * 16 + l15];
    float w3v = W3[t * 16 + l15];
    float dct = dconst[t];   // includes b3
    #pragma unroll
    for (int m = 0; m < 2; ++m) {
        float h2v[4];
        #pragma unroll
        for (int r = 0; r < 4; ++r) {
            float v = c2[m][r] + b2v;
            v = v > 0.f ? v : 0.f;
            h2v[r] = v * w3v;
        }
        #pragma unroll
        for (int off = 1; off < 16; off <<= 1)
            #pragma unroll
            for (int r = 0; r < 4; ++r) h2v[r] += __shfl_xor(h2v[r], off);
        if (l15 == 0) {
            #pragma unroll
            for (int r = 0; r < 4; ++r) {
                int row = rowbase + m * 16 + quad * 4 + r;
                if (row < valid) {
                    unsigned atom = sIds[row];
                    atomicAdd(&out[atom >> 6], h2v[r] + dct);
                }
            }
        }
    }
}

extern "C" void kernel_launch(void* const* d_in, const int* in_sizes, int n_in,
                              void* d_out, int out_size, void* d_ws, size_t ws_size,
                              hipStream_t stream) {
    const float* x    = (const float*)d_in[0];
    const float* mask = (const float*)d_in[1];
    const float* W1   = (const float*)d_in[2];
    const float* b1   = (const float*)d_in[3];
    const float* W2   = (const float*)d_in[4];
    const float* b2   = (const float*)d_in[5];
    const float* W3   = (const float*)d_in[6];
    const float* b3   = (const float*)d_in[7];
    float* out = (float*)d_out;

    char* ws = (char*)d_ws;
    float*          dconst = (float*)(ws + WS_DCONST);
    unsigned*       cursor = (unsigned*)(ws + WS_CURSOR);
    unsigned short* W1S    = (unsigned short*)(ws + WS_W1S);
    unsigned short* W2T    = (unsigned short*)(ws + WS_W2T);
    unsigned*       list   = (unsigned*)(ws + WS_LIST);

    k_setup<<<25, 256, 0, stream>>>(W1, b1, W2, b2, W3, b3, dconst, cursor, W1S, W2T, out);
    k_sort<<<256, 256, 0, stream>>>(x, mask, cursor, list);
    // worst case: all atoms one type -> 2048 tiles; +8 slack for per-type ceil rounding
    k_mlp<<<2056, 256, 0, stream>>>(x, W1S, b1, W2T, b2, W3,
                                    cursor, dconst, list, out);
}